// Round 12
// baseline (302.142 us; speedup 1.0000x reference)
//
#include <hip/hip_runtime.h>
#include <hip/hip_bf16.h>

#define TT 512
#define BPB 16                // two independent 8-batch groups per block
#define NBLK (2048 / BPB)     // 128 blocks
#define OUTD 64

typedef __attribute__((ext_vector_type(8))) short short8;
typedef __attribute__((ext_vector_type(4))) float f32x4;

__device__ __forceinline__ short f2bf(float x) {  // RNE float->bf16 (staging only)
    union { float f; unsigned u; } v; v.f = x;
    unsigned r = (v.u + 0x7FFFu + ((v.u >> 16) & 1u)) >> 16;
    return (short)r;
}
__device__ __forceinline__ short cvt_bf16(float x) {  // 1-instr RNE cvt
    unsigned r;
    asm("v_cvt_pk_bf16_f32 %0, %1, %1" : "=v"(r) : "v"(x));
    return (short)r;
}
__device__ __forceinline__ float sigm(float x) {
    return __builtin_amdgcn_rcpf(1.f + __expf(-x));
}
__device__ __forceinline__ float tanh_fast(float x) {
    return 2.f * sigm(2.f * x) - 1.f;
}

// In-lane LSTM cell update: acc regs = {i,f,g,o} for this lane's (unit,batch)
#define ACT_UPDATE(acc, c, hval)                                   \
    {                                                              \
        float gi = sigm((acc)[0]);                                 \
        float gf = sigm((acc)[1]);                                 \
        float gg = tanh_fast((acc)[2]);                            \
        float go = sigm((acc)[3]);                                 \
        (c) = gf * (c) + gi * gg;                                  \
        (hval) = go * tanh_fast((c));                              \
    }

// Fold tile1's valid batch-columns (col<8) into tile0's junk columns (col>=8).
#define MERGE(mg, a0, a1, colhi)                                   \
    {                                                              \
        _Pragma("unroll")                                          \
        for (int r = 0; r < 4; ++r) {                              \
            float s = __shfl_xor((a1)[r], 8);                      \
            (mg)[r] = (colhi) ? s : (a0)[r];                       \
        }                                                          \
    }

__global__ __launch_bounds__(512, 1) void lstm2_dual_kernel(
    const float* __restrict__ imu,
    const float* __restrict__ w_ih0, const float* __restrict__ w_hh0,
    const float* __restrict__ b_ih0, const float* __restrict__ b_hh0,
    const float* __restrict__ w_ih1, const float* __restrict__ w_hh1,
    const float* __restrict__ b_ih1, const float* __restrict__ b_hh1,
    const float* __restrict__ wf, const float* __restrict__ bf,
    const float* __restrict__ wn, const float* __restrict__ bn,
    float* __restrict__ out)
{
    const int tid   = threadIdx.x;
    const int l     = tid & 63;
    const int w     = tid >> 6;          // 8 waves
    const int layer = w >> 2;            // 0: LSTM1, 1: LSTM2
    const int pair  = w & 3;             // which pair of 16-gate tiles
    const int col   = l & 15;            // B col (0-7 valid per group); A row m
    const int kg    = l >> 4;            // k-group (and D row-quad)
    const bool colhi = (col >= 8);
    const int batch  = col & 7;          // batch within group

    __shared__ __align__(16) short xfrag[TT + 4][BPB][8]; // [t][batch16][k]; +4 pad
    __shared__ __align__(16) short h1f[2][2][16][40];     // [group][parity][row][unit]
    __shared__ __align__(16) short h2f[2][2][16][40];
    __shared__ __align__(16) float lasth[16][36];         // [batch16][unit] fp32

    // ---- zero h buffers and xfrag pad rows
    {
        short* p1 = &h1f[0][0][0][0];
        short* p2 = &h2f[0][0][0][0];
        for (int i = tid; i < 2 * 2 * 16 * 40; i += 512) { p1[i] = 0; p2[i] = 0; }
        short* px = &xfrag[TT][0][0];
        if (tid < 4 * BPB * 8) px[tid] = 0;
    }

    // ---- stage x into [t][batch16][k] bf16
    {
        const int bg0 = blockIdx.x * BPB;
        for (int p = tid; p < BPB * TT; p += 512) {
            const int bb = p >> 9;           // 0..15
            const int t  = p & (TT - 1);
            const float* src = imu + ((size_t)(bg0 + bb) * TT + t) * 6;
            float2 a0 = *(const float2*)(src);
            float2 a1 = *(const float2*)(src + 2);
            float2 a2 = *(const float2*)(src + 4);
            unsigned* dst = (unsigned*)&xfrag[t][bb][0];
            dst[0] = (unsigned short)f2bf(a0.x) | ((unsigned)(unsigned short)f2bf(a0.y) << 16);
            dst[1] = (unsigned short)f2bf(a1.x) | ((unsigned)(unsigned short)f2bf(a1.y) << 16);
            dst[2] = (unsigned short)f2bf(a2.x) | ((unsigned)(unsigned short)f2bf(a2.y) << 16);
            dst[3] = 0u;
        }
    }

    // ---- A-fragments (shared by both groups): unit-major gate order.
    const int t0 = pair * 2, t1 = t0 + 1;
    const int m  = col;
    const int G0 = (m & 3) * 32 + t0 * 4 + (m >> 2);
    const int G1 = (m & 3) * 32 + t1 * 4 + (m >> 2);
    const int u0 = pair * 8 + kg;
    const int u1 = u0 + 4;
    const int myunit = u0 + (colhi ? 4 : 0);

    short8 A00, A01, A10, A11;
    f32x4 bias0, bias1;
    if (layer == 0) {
        #pragma unroll
        for (int j = 0; j < 8; ++j) {
            A00[j] = (kg == 0 && j < 6) ? f2bf(w_ih0[G0 * 6 + j]) : (short)0;
            A10[j] = (kg == 0 && j < 6) ? f2bf(w_ih0[G1 * 6 + j]) : (short)0;
            A01[j] = f2bf(w_hh0[G0 * 32 + kg * 8 + j]);
            A11[j] = f2bf(w_hh0[G1 * 32 + kg * 8 + j]);
        }
        #pragma unroll
        for (int r = 0; r < 4; ++r) {
            bias0[r] = b_ih0[r * 32 + u0] + b_hh0[r * 32 + u0];
            bias1[r] = b_ih0[r * 32 + u1] + b_hh0[r * 32 + u1];
        }
    } else {
        #pragma unroll
        for (int j = 0; j < 8; ++j) {
            A00[j] = f2bf(w_ih1[G0 * 32 + kg * 8 + j]);
            A10[j] = f2bf(w_ih1[G1 * 32 + kg * 8 + j]);
            A01[j] = f2bf(w_hh1[G0 * 32 + kg * 8 + j]);
            A11[j] = f2bf(w_hh1[G1 * 32 + kg * 8 + j]);
        }
        #pragma unroll
        for (int r = 0; r < 4; ++r) {
            bias0[r] = b_ih1[r * 32 + u0] + b_hh1[r * 32 + u0];
            bias1[r] = b_ih1[r * 32 + u1] + b_hh1[r * 32 + u1];
        }
    }

    float cA = 0.f, cB = 0.f;            // cell state, group A / B

    const int xbA = l & 7;               // x batch for group A (L1 lanes)
    const int xbB = (l & 7) + 8;         // x batch for group B
    const short8* h1A0 = (const short8*)&h1f[0][0][col][kg * 8];
    const short8* h1A1 = (const short8*)&h1f[0][1][col][kg * 8];
    const short8* h1B0 = (const short8*)&h1f[1][0][col][kg * 8];
    const short8* h1B1 = (const short8*)&h1f[1][1][col][kg * 8];
    const short8* h2A0 = (const short8*)&h2f[0][0][col][kg * 8];
    const short8* h2A1 = (const short8*)&h2f[0][1][col][kg * 8];
    const short8* h2B0 = (const short8*)&h2f[1][0][col][kg * 8];
    const short8* h2B1 = (const short8*)&h2f[1][1][col][kg * 8];

    __syncthreads();

    // ======== prologue: L1 gates(0) for both groups; prime x-partials ========
    short8 xvEA = (short8)0, xvOA = (short8)0;
    short8 xvEB = (short8)0, xvOB = (short8)0;
    f32x4 xaccA0 = bias0, xaccA1 = bias1, xaccB0 = bias0, xaccB1 = bias1;
    if (layer == 0) {
        short8 xvA = *(const short8*)&xfrag[0][xbA][0];
        short8 xvB = *(const short8*)&xfrag[0][xbB][0];
        f32x4 aA0 = __builtin_amdgcn_mfma_f32_16x16x32_bf16(A00, xvA, bias0, 0, 0, 0);
        f32x4 aA1 = __builtin_amdgcn_mfma_f32_16x16x32_bf16(A10, xvA, bias1, 0, 0, 0);
        f32x4 aB0 = __builtin_amdgcn_mfma_f32_16x16x32_bf16(A00, xvB, bias0, 0, 0, 0);
        f32x4 aB1 = __builtin_amdgcn_mfma_f32_16x16x32_bf16(A10, xvB, bias1, 0, 0, 0);
        f32x4 mgA, mgB;
        MERGE(mgA, aA0, aA1, colhi);
        MERGE(mgB, aB0, aB1, colhi);
        float hA, hB;
        ACT_UPDATE(mgA, cA, hA);
        ACT_UPDATE(mgB, cB, hB);
        h1f[0][1][batch][myunit] = cvt_bf16(hA);
        h1f[1][1][batch][myunit] = cvt_bf16(hB);
        short8 x1A = *(const short8*)&xfrag[1][xbA][0];
        short8 x1B = *(const short8*)&xfrag[1][xbB][0];
        xaccA0 = __builtin_amdgcn_mfma_f32_16x16x32_bf16(A00, x1A, bias0, 0, 0, 0);
        xaccA1 = __builtin_amdgcn_mfma_f32_16x16x32_bf16(A10, x1A, bias1, 0, 0, 0);
        xaccB0 = __builtin_amdgcn_mfma_f32_16x16x32_bf16(A00, x1B, bias0, 0, 0, 0);
        xaccB1 = __builtin_amdgcn_mfma_f32_16x16x32_bf16(A10, x1B, bias1, 0, 0, 0);
        xvEA = *(const short8*)&xfrag[2][xbA][0];
        xvEB = *(const short8*)&xfrag[2][xbB][0];
    }
    __syncthreads();

    // ======== main loop: STEP(T) = {L1(T+1) || L2(T)} for groups A and B ========
#define STEP(T, H1RA, H1RB, H2RA, H2RB, WP, XVCA, XVLA, XVCB, XVLB)             \
    {                                                                           \
        if (layer == 0) {                                                       \
            short8 hvA = *(H1RA);                                               \
            short8 hvB = *(H1RB);                                               \
            f32x4 aA0 = __builtin_amdgcn_mfma_f32_16x16x32_bf16(A01, hvA, xaccA0, 0, 0, 0); \
            f32x4 aA1 = __builtin_amdgcn_mfma_f32_16x16x32_bf16(A11, hvA, xaccA1, 0, 0, 0); \
            f32x4 aB0 = __builtin_amdgcn_mfma_f32_16x16x32_bf16(A01, hvB, xaccB0, 0, 0, 0); \
            f32x4 aB1 = __builtin_amdgcn_mfma_f32_16x16x32_bf16(A11, hvB, xaccB1, 0, 0, 0); \
            f32x4 mgA, mgB;                                                     \
            MERGE(mgA, aA0, aA1, colhi);                                        \
            MERGE(mgB, aB0, aB1, colhi);                                        \
            float hA, hB;                                                       \
            ACT_UPDATE(mgA, cA, hA);                                            \
            ACT_UPDATE(mgB, cB, hB);                                            \
            h1f[0][WP][batch][myunit] = cvt_bf16(hA);                           \
            h1f[1][WP][batch][myunit] = cvt_bf16(hB);                           \
            xaccA0 = __builtin_amdgcn_mfma_f32_16x16x32_bf16(A00, XVCA, bias0, 0, 0, 0); \
            xaccA1 = __builtin_amdgcn_mfma_f32_16x16x32_bf16(A10, XVCA, bias1, 0, 0, 0); \
            xaccB0 = __builtin_amdgcn_mfma_f32_16x16x32_bf16(A00, XVCB, bias0, 0, 0, 0); \
            xaccB1 = __builtin_amdgcn_mfma_f32_16x16x32_bf16(A10, XVCB, bias1, 0, 0, 0); \
            XVLA = *(const short8*)&xfrag[(T) + 3][xbA][0];                     \
            XVLB = *(const short8*)&xfrag[(T) + 3][xbB][0];                     \
        } else {                                                                \
            short8 avA = *(H1RA);                                               \
            short8 avB = *(H1RB);                                               \
            short8 bvA = *(H2RA);                                               \
            short8 bvB = *(H2RB);                                               \
            f32x4 aA0 = __builtin_amdgcn_mfma_f32_16x16x32_bf16(A00, avA, bias0, 0, 0, 0); \
            f32x4 aA1 = __builtin_amdgcn_mfma_f32_16x16x32_bf16(A10, avA, bias1, 0, 0, 0); \
            f32x4 aB0 = __builtin_amdgcn_mfma_f32_16x16x32_bf16(A00, avB, bias0, 0, 0, 0); \
            f32x4 aB1 = __builtin_amdgcn_mfma_f32_16x16x32_bf16(A10, avB, bias1, 0, 0, 0); \
            aA0 = __builtin_amdgcn_mfma_f32_16x16x32_bf16(A01, bvA, aA0, 0, 0, 0); \
            aA1 = __builtin_amdgcn_mfma_f32_16x16x32_bf16(A11, bvA, aA1, 0, 0, 0); \
            aB0 = __builtin_amdgcn_mfma_f32_16x16x32_bf16(A01, bvB, aB0, 0, 0, 0); \
            aB1 = __builtin_amdgcn_mfma_f32_16x16x32_bf16(A11, bvB, aB1, 0, 0, 0); \
            f32x4 mgA, mgB;                                                     \
            MERGE(mgA, aA0, aA1, colhi);                                        \
            MERGE(mgB, aB0, aB1, colhi);                                        \
            float hA, hB;                                                       \
            ACT_UPDATE(mgA, cA, hA);                                            \
            ACT_UPDATE(mgB, cB, hB);                                            \
            h2f[0][WP][batch][myunit] = cvt_bf16(hA);                           \
            h2f[1][WP][batch][myunit] = cvt_bf16(hB);                           \
        }                                                                       \
        __syncthreads();                                                        \
    }

    #pragma unroll 1
    for (int t = 0; t < TT - 2; t += 2) {
        STEP(t,     h1A1, h1B1, h2A1, h2B1, 0, xvEA, xvOA, xvEB, xvOB)
        STEP(t + 1, h1A0, h1B0, h2A0, h2B0, 1, xvOA, xvEA, xvOB, xvEB)
    }
    STEP(TT - 2, h1A1, h1B1, h2A1, h2B1, 0, xvEA, xvOA, xvEB, xvOB)  // T=510

    // ======== epilogue: L2 gates(511) both groups -> lasth (fp32) ========
    if (layer == 1) {
        short8 avA = *h1A0;          // h1(511) at parity 0
        short8 avB = *h1B0;
        short8 bvA = *h2A0;          // h2(510) at parity 0
        short8 bvB = *h2B0;
        f32x4 aA0 = __builtin_amdgcn_mfma_f32_16x16x32_bf16(A00, avA, bias0, 0, 0, 0);
        f32x4 aA1 = __builtin_amdgcn_mfma_f32_16x16x32_bf16(A10, avA, bias1, 0, 0, 0);
        f32x4 aB0 = __builtin_amdgcn_mfma_f32_16x16x32_bf16(A00, avB, bias0, 0, 0, 0);
        f32x4 aB1 = __builtin_amdgcn_mfma_f32_16x16x32_bf16(A10, avB, bias1, 0, 0, 0);
        aA0 = __builtin_amdgcn_mfma_f32_16x16x32_bf16(A01, bvA, aA0, 0, 0, 0);
        aA1 = __builtin_amdgcn_mfma_f32_16x16x32_bf16(A11, bvA, aA1, 0, 0, 0);
        aB0 = __builtin_amdgcn_mfma_f32_16x16x32_bf16(A01, bvB, aB0, 0, 0, 0);
        aB1 = __builtin_amdgcn_mfma_f32_16x16x32_bf16(A11, bvB, aB1, 0, 0, 0);
        f32x4 mgA, mgB;
        MERGE(mgA, aA0, aA1, colhi);
        MERGE(mgB, aB0, aB1, colhi);
        float hA, hB;
        ACT_UPDATE(mgA, cA, hA);
        ACT_UPDATE(mgB, cB, hB);
        lasth[batch][myunit] = hA;
        lasth[batch + 8][myunit] = hB;
    }
    __syncthreads();

    // ======== heads: 2 reps x 512 threads = 16 batches x 64 outputs ========
    #pragma unroll
    for (int rep = 0; rep < 2; ++rep) {
        const int idx = tid + rep * 512;   // 0..1023
        const int bb  = idx >> 6;          // 0..15
        const int o   = idx & 63;
        float accF = bf[o], accN = bn[o];
        const float4* wf4 = (const float4*)(wf + o * 32);
        const float4* wn4 = (const float4*)(wn + o * 32);
        const float4* hv4 = (const float4*)&lasth[bb][0];
        #pragma unroll
        for (int k = 0; k < 8; ++k) {
            float4 h4 = hv4[k];
            float4 f4 = wf4[k];
            float4 n4 = wn4[k];
            accF += f4.x * h4.x + f4.y * h4.y + f4.z * h4.z + f4.w * h4.w;
            accN += n4.x * h4.x + n4.y * h4.y + n4.z * h4.z + n4.w * h4.w;
        }
        const size_t bg = (size_t)blockIdx.x * BPB + bb;
        out[bg * OUTD + o] = accF;
        out[(size_t)2048 * OUTD + bg * OUTD + o] = __expf(accN);
    }
}

extern "C" void kernel_launch(void* const* d_in, const int* in_sizes, int n_in,
                              void* d_out, int out_size, void* d_ws, size_t ws_size,
                              hipStream_t stream) {
    const float* imu   = (const float*)d_in[0];
    const float* w_ih0 = (const float*)d_in[1];
    const float* w_hh0 = (const float*)d_in[2];
    const float* b_ih0 = (const float*)d_in[3];
    const float* b_hh0 = (const float*)d_in[4];
    const float* w_ih1 = (const float*)d_in[5];
    const float* w_hh1 = (const float*)d_in[6];
    const float* b_ih1 = (const float*)d_in[7];
    const float* b_hh1 = (const float*)d_in[8];
    const float* wf    = (const float*)d_in[9];
    const float* bf    = (const float*)d_in[10];
    const float* wn    = (const float*)d_in[11];
    const float* bn    = (const float*)d_in[12];
    float* out = (float*)d_out;

    lstm2_dual_kernel<<<dim3(NBLK), dim3(512), 0, stream>>>(
        imu, w_ih0, w_hh0, b_ih0, b_hh0,
        w_ih1, w_hh1, b_ih1, b_hh1,
        wf, bf, wn, bn, out);
}

// Round 13
// 180.241 us; speedup vs baseline: 1.6763x; 1.6763x over previous
//
#include <hip/hip_runtime.h>
#include <hip/hip_bf16.h>

#define TT 512
#define BPB 8                 // batches per block
#define NBLK (2048 / BPB)     // 256 blocks = 1 per CU
#define OUTD 64

typedef __attribute__((ext_vector_type(8))) short short8;
typedef __attribute__((ext_vector_type(4))) float f32x4;

__device__ __forceinline__ short f2bf(float x) {  // RNE float->bf16 (staging only)
    union { float f; unsigned u; } v; v.f = x;
    unsigned r = (v.u + 0x7FFFu + ((v.u >> 16) & 1u)) >> 16;
    return (short)r;
}
__device__ __forceinline__ short cvt_bf16(float x) {  // 1-instr RNE cvt
    unsigned r;
    asm("v_cvt_pk_bf16_f32 %0, %1, %1" : "=v"(r) : "v"(x));
    return (short)r;
}
__device__ __forceinline__ float sigm(float x) {
    return __builtin_amdgcn_rcpf(1.f + __expf(-x));
}
__device__ __forceinline__ float tanh_fast(float x) {
    return 2.f * sigm(2.f * x) - 1.f;
}

// In-lane LSTM cell update: acc regs = {i,f,g,o} for this lane's (unit,batch)
#define ACT_UPDATE(acc, c, hval)                                   \
    {                                                              \
        float gi = sigm((acc)[0]);                                 \
        float gf = sigm((acc)[1]);                                 \
        float gg = tanh_fast((acc)[2]);                            \
        float go = sigm((acc)[3]);                                 \
        (c) = gf * (c) + gi * gg;                                  \
        (hval) = go * tanh_fast((c));                              \
    }

// Fold tile1's valid batch-columns (col<8) into tile0's junk columns (col>=8).
#define MERGE(mg, a0, a1, colhi)                                   \
    {                                                              \
        _Pragma("unroll")                                          \
        for (int r = 0; r < 4; ++r) {                              \
            float s = __shfl_xor((a1)[r], 8);                      \
            (mg)[r] = (colhi) ? s : (a0)[r];                       \
        }                                                          \
    }

__global__ __launch_bounds__(512, 1) void lstm2_inlane_kernel(
    const float* __restrict__ imu,
    const float* __restrict__ w_ih0, const float* __restrict__ w_hh0,
    const float* __restrict__ b_ih0, const float* __restrict__ b_hh0,
    const float* __restrict__ w_ih1, const float* __restrict__ w_hh1,
    const float* __restrict__ b_ih1, const float* __restrict__ b_hh1,
    const float* __restrict__ wf, const float* __restrict__ bf,
    const float* __restrict__ wn, const float* __restrict__ bn,
    float* __restrict__ out)
{
    const int tid   = threadIdx.x;
    const int l     = tid & 63;
    const int w     = tid >> 6;          // 8 waves
    const int layer = w >> 2;            // 0: LSTM1, 1: LSTM2
    const int pair  = w & 3;             // which pair of 16-gate tiles
    const int col   = l & 15;            // B col = batch (0-7 valid); A row m
    const int kg    = l >> 4;            // k-group (and D row-quad)
    const bool colhi = (col >= 8);
    const int batch  = col & 7;

    __shared__ __align__(16) short xfrag[TT + 4][BPB][8];  // [t][batch][k] bf16; +4 pad
    __shared__ __align__(16) short h1f[2][16][40];         // [parity][batch][unit] bf16
    __shared__ __align__(16) short h2f[2][16][40];
    __shared__ __align__(16) float lasth[16][36];          // [batch][unit] fp32

    // ---- zero h buffers (and pad rows of xfrag)
    {
        short* p1 = &h1f[0][0][0];
        short* p2 = &h2f[0][0][0];
        for (int i = tid; i < 2 * 16 * 40; i += 512) { p1[i] = 0; p2[i] = 0; }
        short* px = &xfrag[TT][0][0];
        for (int i = tid; i < 4 * BPB * 8; i += 512) px[i] = 0;
    }

    // ---- stage x into [t][batch][k] bf16
    {
        const int bg0 = blockIdx.x * BPB;
        for (int p = tid; p < BPB * TT; p += 512) {
            const int b = p >> 9;            // 0..7
            const int t = p & (TT - 1);
            const float* src = imu + ((size_t)(bg0 + b) * TT + t) * 6;
            float2 a0 = *(const float2*)(src);
            float2 a1 = *(const float2*)(src + 2);
            float2 a2 = *(const float2*)(src + 4);
            unsigned* dst = (unsigned*)&xfrag[t][b][0];
            dst[0] = (unsigned short)f2bf(a0.x) | ((unsigned)(unsigned short)f2bf(a0.y) << 16);
            dst[1] = (unsigned short)f2bf(a1.x) | ((unsigned)(unsigned short)f2bf(a1.y) << 16);
            dst[2] = (unsigned short)f2bf(a2.x) | ((unsigned)(unsigned short)f2bf(a2.y) << 16);
            dst[3] = 0u;
        }
    }

    // ---- A-fragments: rows = weight rows, unit-major gate order (natural K).
    const int t0 = pair * 2, t1 = t0 + 1;
    const int m  = col;
    const int G0 = (m & 3) * 32 + t0 * 4 + (m >> 2);
    const int G1 = (m & 3) * 32 + t1 * 4 + (m >> 2);
    const int u0 = pair * 8 + kg;        // tile0 unit of this lane
    const int u1 = u0 + 4;               // tile1 unit
    const int myunit = u0 + (colhi ? 4 : 0);   // owned unit after MERGE

    short8 A00, A01, A10, A11;           // [tile][x-or-first / h-or-second]
    f32x4 bias0, bias1;
    if (layer == 0) {
        #pragma unroll
        for (int j = 0; j < 8; ++j) {
            A00[j] = (kg == 0 && j < 6) ? f2bf(w_ih0[G0 * 6 + j]) : (short)0;
            A10[j] = (kg == 0 && j < 6) ? f2bf(w_ih0[G1 * 6 + j]) : (short)0;
            A01[j] = f2bf(w_hh0[G0 * 32 + kg * 8 + j]);
            A11[j] = f2bf(w_hh0[G1 * 32 + kg * 8 + j]);
        }
        #pragma unroll
        for (int r = 0; r < 4; ++r) {
            bias0[r] = b_ih0[r * 32 + u0] + b_hh0[r * 32 + u0];
            bias1[r] = b_ih0[r * 32 + u1] + b_hh0[r * 32 + u1];
        }
    } else {
        #pragma unroll
        for (int j = 0; j < 8; ++j) {
            A00[j] = f2bf(w_ih1[G0 * 32 + kg * 8 + j]);
            A10[j] = f2bf(w_ih1[G1 * 32 + kg * 8 + j]);
            A01[j] = f2bf(w_hh1[G0 * 32 + kg * 8 + j]);
            A11[j] = f2bf(w_hh1[G1 * 32 + kg * 8 + j]);
        }
        #pragma unroll
        for (int r = 0; r < 4; ++r) {
            bias0[r] = b_ih1[r * 32 + u0] + b_hh1[r * 32 + u0];
            bias1[r] = b_ih1[r * 32 + u1] + b_hh1[r * 32 + u1];
        }
    }

    float c = 0.f;                       // this lane's single cell state

    const int xb = l & 7;                // batch whose x this lane feeds
    const short8* h1r0  = (const short8*)&h1f[0][col][kg * 8];
    const short8* h1r1  = (const short8*)&h1f[1][col][kg * 8];
    const short8* h2r0  = (const short8*)&h2f[0][col][kg * 8];
    const short8* h2r1  = (const short8*)&h2f[1][col][kg * 8];

    __syncthreads();

    // ======== prologue: L1 gates(0) with h1=0; prime xacc (x(1)-partial) ========
    short8 xvE = (short8)0, xvO = (short8)0;  // x prefetch regs (even/odd phases)
    f32x4 xacc0 = bias0, xacc1 = bias1;       // x-partial for next step's gates
    if (layer == 0) {
        short8 xv = *(const short8*)&xfrag[0][xb][0];
        f32x4 a0 = __builtin_amdgcn_mfma_f32_16x16x32_bf16(A00, xv, bias0, 0, 0, 0);
        f32x4 a1 = __builtin_amdgcn_mfma_f32_16x16x32_bf16(A10, xv, bias1, 0, 0, 0);
        f32x4 mg;
        MERGE(mg, a0, a1, colhi);
        float h;
        ACT_UPDATE(mg, c, h);
        h1f[1][batch][myunit] = cvt_bf16(h);
        short8 xv1 = *(const short8*)&xfrag[1][xb][0];
        xacc0 = __builtin_amdgcn_mfma_f32_16x16x32_bf16(A00, xv1, bias0, 0, 0, 0);
        xacc1 = __builtin_amdgcn_mfma_f32_16x16x32_bf16(A10, xv1, bias1, 0, 0, 0);
        xvE = *(const short8*)&xfrag[2][xb][0];   // drains in barrier
    }
    __syncthreads();

    // ======== main loop: STEP(T) = L1 gates(T+1) || L2 gates(T) ========
    // Precise-wait barrier: L1 leaves its x-prefetch ds_read IN FLIGHT across
    // the barrier (lgkmcnt(1): the h ds_write — older, LDS in-order — is done);
    // L2 drains only its h write (lgkmcnt(0), short). Raw s_barrier (no full
    // drain like __syncthreads). Empty memory-asm pins write-before-read order.
#define STEP(T, H1R, H2R, WP, XVC, XVL)                                         \
    {                                                                           \
        if (layer == 0) {                                                       \
            short8 hv = *(H1R);                                                 \
            f32x4 a0 = __builtin_amdgcn_mfma_f32_16x16x32_bf16(A01, hv, xacc0, 0, 0, 0); \
            f32x4 a1 = __builtin_amdgcn_mfma_f32_16x16x32_bf16(A11, hv, xacc1, 0, 0, 0); \
            f32x4 mg;                                                           \
            MERGE(mg, a0, a1, colhi);                                           \
            float h;                                                            \
            ACT_UPDATE(mg, c, h);                                               \
            h1f[WP][batch][myunit] = cvt_bf16(h);                               \
            xacc0 = __builtin_amdgcn_mfma_f32_16x16x32_bf16(A00, XVC, bias0, 0, 0, 0); \
            xacc1 = __builtin_amdgcn_mfma_f32_16x16x32_bf16(A10, XVC, bias1, 0, 0, 0); \
            asm volatile("" ::: "memory");  /* pin h-write before x-read */     \
            XVL = *(const short8*)&xfrag[(T) + 3][xb][0];                       \
            asm volatile("s_waitcnt lgkmcnt(1)" ::: "memory");                  \
        } else {                                                                \
            short8 av = *(H1R);                                                 \
            short8 bv = *(H2R);                                                 \
            f32x4 a0 = __builtin_amdgcn_mfma_f32_16x16x32_bf16(A00, av, bias0, 0, 0, 0); \
            f32x4 a1 = __builtin_amdgcn_mfma_f32_16x16x32_bf16(A10, av, bias1, 0, 0, 0); \
            a0 = __builtin_amdgcn_mfma_f32_16x16x32_bf16(A01, bv, a0, 0, 0, 0); \
            a1 = __builtin_amdgcn_mfma_f32_16x16x32_bf16(A11, bv, a1, 0, 0, 0); \
            f32x4 mg;                                                           \
            MERGE(mg, a0, a1, colhi);                                           \
            float h;                                                            \
            ACT_UPDATE(mg, c, h);                                               \
            h2f[WP][batch][myunit] = cvt_bf16(h);                               \
            asm volatile("s_waitcnt lgkmcnt(0)" ::: "memory");                  \
        }                                                                       \
        __builtin_amdgcn_s_barrier();                                           \
        asm volatile("" ::: "memory");                                          \
    }

    #pragma unroll 1
    for (int t = 0; t < TT - 2; t += 2) {
        STEP(t,     h1r1, h2r1, 0, xvE, xvO)   // even T: read parity 1, write 0
        STEP(t + 1, h1r0, h2r0, 1, xvO, xvE)   // odd  T: read parity 0, write 1
    }
    STEP(TT - 2, h1r1, h2r1, 0, xvE, xvO)      // T=510 (prefetch hits pad rows)

    // ======== epilogue: L2 gates(511) -> lasth (fp32) ========
    if (layer == 1) {
        short8 av = *h1r0;           // h1(511) at parity 0
        short8 bv = *h2r0;           // h2(510) at parity 0
        f32x4 a0 = __builtin_amdgcn_mfma_f32_16x16x32_bf16(A00, av, bias0, 0, 0, 0);
        f32x4 a1 = __builtin_amdgcn_mfma_f32_16x16x32_bf16(A10, av, bias1, 0, 0, 0);
        a0 = __builtin_amdgcn_mfma_f32_16x16x32_bf16(A01, bv, a0, 0, 0, 0);
        a1 = __builtin_amdgcn_mfma_f32_16x16x32_bf16(A11, bv, a1, 0, 0, 0);
        f32x4 mg;
        MERGE(mg, a0, a1, colhi);
        float h;
        ACT_UPDATE(mg, c, h);
        lasth[batch][myunit] = h;
    }
    __syncthreads();

    // ======== heads: 512 threads = 8 batches x 64 outputs ========
    {
        const int b = tid >> 6;            // 0..7 (wave-uniform)
        const int o = tid & 63;
        float accF = bf[o], accN = bn[o];
        const float4* wf4 = (const float4*)(wf + o * 32);
        const float4* wn4 = (const float4*)(wn + o * 32);
        const float4* hv4 = (const float4*)&lasth[b][0];
        #pragma unroll
        for (int k = 0; k < 8; ++k) {
            float4 h4 = hv4[k];
            float4 f4 = wf4[k];
            float4 n4 = wn4[k];
            accF += f4.x * h4.x + f4.y * h4.y + f4.z * h4.z + f4.w * h4.w;
            accN += n4.x * h4.x + n4.y * h4.y + n4.z * h4.z + n4.w * h4.w;
        }
        const size_t bg = (size_t)blockIdx.x * BPB + b;
        out[bg * OUTD + o] = accF;
        out[(size_t)2048 * OUTD + bg * OUTD + o] = __expf(accN);
    }
}

extern "C" void kernel_launch(void* const* d_in, const int* in_sizes, int n_in,
                              void* d_out, int out_size, void* d_ws, size_t ws_size,
                              hipStream_t stream) {
    const float* imu   = (const float*)d_in[0];
    const float* w_ih0 = (const float*)d_in[1];
    const float* w_hh0 = (const float*)d_in[2];
    const float* b_ih0 = (const float*)d_in[3];
    const float* b_hh0 = (const float*)d_in[4];
    const float* w_ih1 = (const float*)d_in[5];
    const float* w_hh1 = (const float*)d_in[6];
    const float* b_ih1 = (const float*)d_in[7];
    const float* b_hh1 = (const float*)d_in[8];
    const float* wf    = (const float*)d_in[9];
    const float* bf    = (const float*)d_in[10];
    const float* wn    = (const float*)d_in[11];
    const float* bn    = (const float*)d_in[12];
    float* out = (float*)d_out;

    lstm2_inlane_kernel<<<dim3(NBLK), dim3(512), 0, stream>>>(
        imu, w_ih0, w_hh0, b_ih0, b_hh0,
        w_ih1, w_hh1, b_ih1, b_hh1,
        wf, bf, wn, bn, out);
}